// Round 13
// baseline (714.023 us; speedup 1.0000x reference)
//
#include <hip/hip_runtime.h>
#include <stdint.h>

namespace {
constexpr int Wd = 960, Hd = 544, Cd = 16, Id = 5, Bd = 2;
constexpr int HW = Hd * Wd;                       // 522240
constexpr long CHW = (long)Cd * HW;               // 8,355,840
constexpr long FRAME_BSTRIDE = (long)Id * CHW;
constexpr long FLOW_BSTRIDE  = (long)Id * 2 * HW;

constexpr int TSX = 64, TSY = 32;   // output tile, 512 thr x 4 px
constexpr int HALO = 12;            // 3 sigma of 4px flow; tails -> fallback
constexpr int TWX = TSX + 2 * HALO; // 88
constexpr int TWY = TSY + 2 * HALO; // 56
constexpr int NCHUNK = 20;          // 20 x 256 floats = 5120 >= 88*56
constexpr int TILE_F = NCHUNK * 256;

// fused-2 geometry: two warp levels in one kernel
constexpr int HIN  = 2 * HALO;        // 24 src halo
constexpr int SRCW = TSX + 2 * HIN;   // 112
constexpr int SRCH = TSY + 2 * HIN;   // 80
constexpr int SRC_F = SRCW * SRCH;    // 8960 = 35 chunks x 256 exactly
constexpr int SCHUNK = 35;
constexpr int IW = TWX, IH = TWY;     // intermediate tile 88 x 56
constexpr int I_F = IW * IH;          // 4928

constexpr int GX = Wd / TSX;        // 15
constexpr int GY = Hd / TSY;        // 17
constexpr int NWG = GX * GY * Bd;   // 510
}

struct F2 { float x, y; };
struct Job  { const void* s; long ss; void* d; long ds; const float* fl; int sBF, dBF; };
struct Job2 { const void* s; long ss; void* d; long ds;
              const float* flA; const float* flB; int dBF; };

__device__ __forceinline__ uint f2bf_bits(float v) {   // RNE float->bf16
  uint x = __float_as_uint(v);
  return (x + 0x7FFFu + ((x >> 16) & 1u)) >> 16;
}

#define DECODE_TILE()                                                        \
  const int orig = blockIdx.x;                                               \
  const int xcd  = orig & 7;                                                 \
  constexpr int q = NWG / 8, r = NWG % 8;                                    \
  const int wgid = (xcd < r ? xcd * (q + 1) : r * (q + 1) + (xcd - r) * q)   \
                 + (orig >> 3);                                              \
  const int b   = wgid / (GX * GY);                                          \
  const int rem = wgid - b * (GX * GY);                                      \
  const int tyb = rem / GX;                                                  \
  const int txb = rem - tyb * GX;                                            \
  const int X0 = txb * TSX;                                                  \
  const int Y0 = tyb * TSY;                                                  \
  const int t   = threadIdx.x;                                               \
  const int x   = X0 + ((t & 15) << 2);                                      \
  const int y   = Y0 + (t >> 4);                                             \
  const int pix = y * Wd + x;

// SC_: 4 -> byte offset (F2 reads), 1 -> float index
#define PRECOMPUTE_WEIGHTS(HALO_, TWX_, TWY_, SC_)                           \
  float4 fxv = *reinterpret_cast<const float4*>(fl + pix);                   \
  float4 fyv = *reinterpret_cast<const float4*>(fl + HW + pix);              \
  float w00[4], w10[4], w01[4], w11[4];                                      \
  int lA[4]; uint32_t pxy[4]; int fbm = 0;                                   \
  _Pragma("unroll")                                                          \
  for (int j = 0; j < 4; ++j) {                                              \
    float fx = (j==0)?fxv.x:(j==1)?fxv.y:(j==2)?fxv.z:fxv.w;                 \
    float fy = (j==0)?fyv.x:(j==1)?fyv.y:(j==2)?fyv.z:fyv.w;                 \
    float gx = (float)(x + j) + fx;                                          \
    float gy = (float)y + fy;                                                \
    float x0f = floorf(gx), y0f = floorf(gy);                                \
    float wx = gx - x0f, wy = gy - y0f;                                      \
    bool vx0 = (x0f >= 0.f) && (x0f <= (float)(Wd - 1));                     \
    bool vx1 = (x0f + 1.f >= 0.f) && (x0f + 1.f <= (float)(Wd - 1));         \
    bool vy0 = (y0f >= 0.f) && (y0f <= (float)(Hd - 1));                     \
    bool vy1 = (y0f + 1.f >= 0.f) && (y0f + 1.f <= (float)(Hd - 1));         \
    w00[j] = (1.f-wx)*(1.f-wy) * ((vx0 && vy0) ? 1.f : 0.f);                 \
    w10[j] = wx*(1.f-wy)       * ((vx1 && vy0) ? 1.f : 0.f);                 \
    w01[j] = (1.f-wx)*wy       * ((vx0 && vy1) ? 1.f : 0.f);                 \
    w11[j] = wx*wy             * ((vx1 && vy1) ? 1.f : 0.f);                 \
    int ix0 = (int)x0f;                                                      \
    int iy0 = (int)y0f;                                                      \
    int lx = ix0 - (X0 - (HALO_));                                           \
    int ly = iy0 - (Y0 - (HALO_));                                           \
    bool ft = (lx >= 0) & (lx <= (TWX_) - 2) & (ly >= 0) & (ly <= (TWY_) - 2);\
    if (!ft) fbm |= (1 << j);                                                \
    int lxc = min(max(lx, 0), (TWX_) - 2), lyc = min(max(ly, 0), (TWY_) - 2);\
    lA[j] = (lyc * (TWX_) + lxc) * (SC_);                                    \
    uint32_t px_ = (uint32_t)min(max(ix0 + 128, 0), 65535);                  \
    uint32_t py_ = (uint32_t)min(max(iy0 + 128, 0), 65535);                  \
    pxy[j] = px_ | (py_ << 16);                                              \
  }

#define WAITV(n3, n2)                                                        \
  if (wv < 4) { asm volatile("s_waitcnt vmcnt(" #n3 ")" ::: "memory"); }     \
  else        { asm volatile("s_waitcnt vmcnt(" #n2 ")" ::: "memory"); }

// =============== pipelined fp32-source single-warp kernel (round-9 proven) =
#define PHASE(c, n3, n2)                                                     \
  WAITV(n3, n2);                                                             \
  __builtin_amdgcn_s_barrier();                                              \
  __builtin_amdgcn_sched_barrier(0);                                         \
  if ((c) + 3 < Cd) fillq(((c) + 3) & 3, (c) + 3);                           \
  comp(c);

__global__ __launch_bounds__(512, 4) void warp_pipe(
    Job j0, Job j1, Job j2, Job j3, Job j4)
{
  __shared__ float tile[4 * TILE_F];   // 80 KB -> 2 blocks/CU

  const int jb = blockIdx.y;
  Job J = j0;
  if      (jb == 1) J = j1;
  else if (jb == 2) J = j2;
  else if (jb == 3) J = j3;
  else if (jb == 4) J = j4;

  DECODE_TILE();

  const float* sF32 = (const float*)J.s + (long)b * J.ss;
  float*       dF32 = (float*)J.d + (long)b * J.ds;
  uint16_t*    dB16 = (uint16_t*)J.d + (long)b * J.ds;
  const bool dBF = J.dBF != 0;

  if (J.fl == nullptr) {   // plain fp32 copy job (frame 0); no barriers
#pragma unroll
    for (int c = 0; c < Cd; ++c)
      *reinterpret_cast<float4*>(dF32 + (long)c * HW + pix)
          = *reinterpret_cast<const float4*>(sF32 + (long)c * HW + pix);
    return;
  }

  const float* fl = J.fl + (long)b * FLOW_BSTRIDE;
  PRECOMPUTE_WEIGHTS(HALO, TWX, TWY, 4);

  const int lane = t & 63;
  const int wv   = t >> 6;
  const int nck  = (wv < 4) ? 3 : 2;
  int goff[3];
#pragma unroll
  for (int k = 0; k < 3; ++k) {
    int ck = wv + 8 * k;
    if (ck < NCHUNK) {
      int foff = ck * 256 + lane * 4;
      int ly = foff / TWX;
      int lx = foff - ly * TWX;
      int gxc = min(max(X0 - HALO + lx, 0), Wd - 4);
      int gyc = min(max(Y0 - HALO + ly, 0), Hd - 1);
      goff[k] = gyc * Wd + gxc;
    }
  }

  auto fillq = [&](int buf, int c) {
    const float* sC = sF32 + (long)c * HW;
    float* base = &tile[buf * TILE_F];
#pragma unroll
    for (int k = 0; k < 3; ++k) {
      if (k < nck) {
        __builtin_amdgcn_global_load_lds(
            (__attribute__((address_space(1))) void*)(void*)(sC + goff[k]),
            (__attribute__((address_space(3))) void*)&base[(wv + 8 * k) * 256],
            16, 0, 0);
      }
    }
  };

  auto comp = [&](int c) {
    const float* tb = &tile[(c & 3) * TILE_F];
    float ov[4];
#pragma unroll
    for (int j = 0; j < 4; ++j) {
      F2 r0 = *(const F2*)((const char*)tb + lA[j]);
      F2 r1 = *(const F2*)((const char*)tb + lA[j] + TWX * 4);
      ov[j] = (w00[j] * r0.x + w10[j] * r0.y) + (w01[j] * r1.x + w11[j] * r1.y);
    }
    if (dBF) {
      uint p0 = f2bf_bits(ov[0]) | (f2bf_bits(ov[1]) << 16);
      uint p1 = f2bf_bits(ov[2]) | (f2bf_bits(ov[3]) << 16);
      *reinterpret_cast<uint2*>(dB16 + (long)c * HW + pix) = make_uint2(p0, p1);
    } else {
      *reinterpret_cast<float4*>(dF32 + (long)c * HW + pix)
          = make_float4(ov[0], ov[1], ov[2], ov[3]);
    }
  };

  fillq(0, 0); fillq(1, 1); fillq(2, 2);

  PHASE(0, 6, 4)  PHASE(1, 7, 5)  PHASE(2, 8, 6)
  PHASE(3, 9, 7)  PHASE(4, 9, 7)  PHASE(5, 9, 7)
  PHASE(6, 9, 7)  PHASE(7, 9, 7)  PHASE(8, 9, 7)
  PHASE(9, 9, 7)  PHASE(10, 9, 7) PHASE(11, 9, 7)
  PHASE(12, 9, 7) PHASE(13, 9, 7)
  PHASE(14, 6, 5) PHASE(15, 3, 3)

  if (fbm) {
    asm volatile("s_waitcnt vmcnt(0)" ::: "memory");
    for (int c = 0; c < Cd; ++c) {
      const float* sC = sF32 + (long)c * HW;
#pragma unroll
      for (int j = 0; j < 4; ++j) {
        if (fbm & (1 << j)) {
          uint32_t p = pxy[j];
          int ix0 = (int)(p & 0xffffu) - 128;
          int iy0 = (int)(p >> 16) - 128;
          int xc0 = min(max(ix0, 0), Wd - 1), xc1 = min(max(ix0 + 1, 0), Wd - 1);
          int yc0 = min(max(iy0, 0), Hd - 1), yc1 = min(max(iy0 + 1, 0), Hd - 1);
          float v = w00[j] * sC[yc0 * Wd + xc0] + w10[j] * sC[yc0 * Wd + xc1]
                  + w01[j] * sC[yc1 * Wd + xc0] + w11[j] * sC[yc1 * Wd + xc1];
          if (dBF) dB16[(long)c * HW + pix + j] = (uint16_t)f2bf_bits(v);
          else     dF32[(long)c * HW + pix + j] = v;
        }
      }
    }
  }
}

// =============== fused two-level warp kernel ===============================
// out = warp(warp(src, flB), flA). src tile 112x80 staged in LDS (GLL for
// fp32 src, reg-staged cvt for bf16 src); intermediate I computed on an
// 88x56 LDS tile (10 px/thread, weights precomputed once); outer warp
// gathers from I. Out-of-tile samples use exact global fallbacks.
template <bool SBF>
__global__ __launch_bounds__(512) void warp_fused2(Job2 j0, Job2 j1)
{
  __shared__ float srcT[SRC_F];   // 35 KB
  __shared__ float Ild[I_F];      // 19.25 KB  -> total 55.5 KB, 2 blocks/CU

  Job2 J = (blockIdx.y == 0) ? j0 : j1;

  DECODE_TILE();

  const float*    sF32 = (const float*)J.s + (long)b * J.ss;
  const uint16_t* sB16 = (const uint16_t*)J.s + (long)b * J.ss;
  float*          dF32 = (float*)J.d + (long)b * J.ds;
  uint16_t*       dB16 = (uint16_t*)J.d + (long)b * J.ds;
  const bool dBF = J.dBF != 0;
  const float* flB = J.flB + (long)b * FLOW_BSTRIDE;

  // ---- outer precompute (4 output px/thread), vs intermediate tile ----
  const float* fl = J.flA + (long)b * FLOW_BSTRIDE;
  PRECOMPUTE_WEIGHTS(HALO, IW, IH, 1);   // lA = float index into Ild

  // ---- inner precompute (10 intermediate px/thread) ----
  float wi0[10], wi1[10], wi2[10], wi3[10];
  int   lAi[10];
  uint32_t pxyI[10];
  uint32_t fbmI = 0;
#pragma unroll
  for (int k = 0; k < 10; ++k) {
    int idx = t + 512 * k;
    bool act = (k < 9) || (idx < I_F);
    int iyq = idx / IW;
    int ixq = idx - iyq * IW;
    int qx = X0 - HALO + ixq;
    int qy = Y0 - HALO + iyq;
    int qo = min(max(qy, 0), Hd - 1) * Wd + min(max(qx, 0), Wd - 1);
    float fx = act ? flB[qo] : 0.f;       // clamped read; wrong-flow values
    float fy = act ? flB[HW + qo] : 0.f;  // only land on weight-0 samples
    float gx = (float)qx + fx, gy = (float)qy + fy;
    float x0f = floorf(gx), y0f = floorf(gy);
    float wx = gx - x0f, wy = gy - y0f;
    bool vx0 = (x0f >= 0.f) && (x0f <= (float)(Wd - 1));
    bool vx1 = (x0f + 1.f >= 0.f) && (x0f + 1.f <= (float)(Wd - 1));
    bool vy0 = (y0f >= 0.f) && (y0f <= (float)(Hd - 1));
    bool vy1 = (y0f + 1.f >= 0.f) && (y0f + 1.f <= (float)(Hd - 1));
    wi0[k] = (1.f-wx)*(1.f-wy) * ((vx0 && vy0) ? 1.f : 0.f);
    wi1[k] = wx*(1.f-wy)       * ((vx1 && vy0) ? 1.f : 0.f);
    wi2[k] = (1.f-wx)*wy       * ((vx0 && vy1) ? 1.f : 0.f);
    wi3[k] = wx*wy             * ((vx1 && vy1) ? 1.f : 0.f);
    int ix0 = (int)x0f, iy0 = (int)y0f;
    int lxs = ix0 - (X0 - HIN), lys = iy0 - (Y0 - HIN);
    bool ft = (lxs >= 0) & (lxs <= SRCW - 2) & (lys >= 0) & (lys <= SRCH - 2);
    if (!ft && act) fbmI |= (1u << k);
    int lxc = min(max(lxs, 0), SRCW - 2), lyc = min(max(lys, 0), SRCH - 2);
    lAi[k] = lyc * SRCW + lxc;
    pxyI[k] = (uint32_t)min(max(ix0 + 128, 0), 65535)
            | ((uint32_t)min(max(iy0 + 128, 0), 65535) << 16);
  }

  const int lane = t & 63;
  const int wv   = t >> 6;

  // ---- staging prep ----
  int goffS[5]; int nckS = (wv < 3) ? 5 : 4;   // 35 chunks of 256 floats
  uint2 lb[5];  int goffB[5];
  if constexpr (!SBF) {
#pragma unroll
    for (int m = 0; m < 5; ++m) {
      int ck = wv + 8 * m;
      if (ck < SCHUNK) {
        int foff = ck * 256 + lane * 4;
        int ly2 = foff / SRCW;
        int lx2 = foff - ly2 * SRCW;
        int gxc = min(max(X0 - HIN + lx2, 0), Wd - 4);
        int gyc = min(max(Y0 - HIN + ly2, 0), Hd - 1);
        goffS[m] = gyc * Wd + gxc;
      }
    }
  } else {
#pragma unroll
    for (int k = 0; k < 5; ++k) {
      int f = k * 2048 + t * 4;
      if (f < SRC_F) {
        int ly2 = f / SRCW;
        int lx2 = f - ly2 * SRCW;
        int gxc = min(max(X0 - HIN + lx2, 0), Wd - 4);
        int gyc = min(max(Y0 - HIN + ly2, 0), Hd - 1);
        goffB[k] = gyc * Wd + gxc;
      }
    }
  }

  auto fillS = [&](int c) {
    const float* sC = sF32 + (long)c * HW;
#pragma unroll
    for (int m = 0; m < 5; ++m) {
      if (m < nckS) {
        __builtin_amdgcn_global_load_lds(
            (__attribute__((address_space(1))) void*)(void*)(sC + goffS[m]),
            (__attribute__((address_space(3))) void*)&srcT[(wv + 8 * m) * 256],
            16, 0, 0);
      }
    }
  };
  auto loadB2 = [&](int c) {
    const uint16_t* sC = sB16 + (long)c * HW;
#pragma unroll
    for (int k = 0; k < 5; ++k) {
      bool act = (k < 4) || (t < 192);
      if (act) lb[k] = *(const uint2*)(sC + goffB[k]);
    }
  };
  auto writeB2 = [&]() {
#pragma unroll
    for (int k = 0; k < 5; ++k) {
      bool act = (k < 4) || (t < 192);
      if (act) {
        float4 f4v;
        f4v.x = __uint_as_float(lb[k].x << 16);
        f4v.y = __uint_as_float(lb[k].x & 0xFFFF0000u);
        f4v.z = __uint_as_float(lb[k].y << 16);
        f4v.w = __uint_as_float(lb[k].y & 0xFFFF0000u);
        *reinterpret_cast<float4*>(&srcT[k * 2048 + t * 4]) = f4v;
      }
    }
  };

  auto rdc = [&](int c, int gi) -> float {   // global read, channel c
    if constexpr (SBF) return __uint_as_float((uint)sB16[(long)c * HW + gi] << 16);
    else               return sF32[(long)c * HW + gi];
  };
  // exact I at integer position (outer fallback)
  auto sampleI = [&](int c, int cx, int cy) -> float {
    int cxc = min(max(cx, 0), Wd - 1), cyc = min(max(cy, 0), Hd - 1);
    int co = cyc * Wd + cxc;
    float fx = flB[co], fy = flB[HW + co];
    float gx = (float)cxc + fx, gy = (float)cyc + fy;
    float x0f = floorf(gx), y0f = floorf(gy);
    float wx = gx - x0f, wy = gy - y0f;
    bool vx0 = (x0f >= 0.f) && (x0f <= (float)(Wd - 1));
    bool vx1 = (x0f + 1.f >= 0.f) && (x0f + 1.f <= (float)(Wd - 1));
    bool vy0 = (y0f >= 0.f) && (y0f <= (float)(Hd - 1));
    bool vy1 = (y0f + 1.f >= 0.f) && (y0f + 1.f <= (float)(Hd - 1));
    int ix0 = (int)x0f, iy0 = (int)y0f;
    int xc0 = min(max(ix0, 0), Wd - 1), xc1 = min(max(ix0 + 1, 0), Wd - 1);
    int yc0 = min(max(iy0, 0), Hd - 1), yc1 = min(max(iy0 + 1, 0), Hd - 1);
    float a0 = (1.f-wx)*(1.f-wy) * ((vx0 && vy0) ? 1.f : 0.f);
    float a1 = wx*(1.f-wy)       * ((vx1 && vy0) ? 1.f : 0.f);
    float a2 = (1.f-wx)*wy       * ((vx0 && vy1) ? 1.f : 0.f);
    float a3 = wx*wy             * ((vx1 && vy1) ? 1.f : 0.f);
    return a0 * rdc(c, yc0 * Wd + xc0) + a1 * rdc(c, yc0 * Wd + xc1)
         + a2 * rdc(c, yc1 * Wd + xc0) + a3 * rdc(c, yc1 * Wd + xc1);
  };

  // prologue
  if constexpr (SBF) { loadB2(0); writeB2(); } else fillS(0);
  __syncthreads();

#pragma unroll 1
  for (int c = 0; c < Cd; ++c) {
    if constexpr (SBF) { if (c + 1 < Cd) loadB2(c + 1); }  // regs, in flight

    // ---- I-compute: intermediate warp into Ild ----
#pragma unroll
    for (int k = 0; k < 10; ++k) {
      int idx = t + 512 * k;
      bool act = (k < 9) || (idx < I_F);
      if (act) {
        float v;
        if (!(fbmI & (1u << k))) {
          const float* p = &srcT[lAi[k]];
          v = (wi0[k] * p[0] + wi1[k] * p[1])
            + (wi2[k] * p[SRCW] + wi3[k] * p[SRCW + 1]);
        } else {
          uint32_t pk = pxyI[k];
          int ix0 = (int)(pk & 0xffffu) - 128;
          int iy0 = (int)(pk >> 16) - 128;
          int xc0 = min(max(ix0, 0), Wd - 1), xc1 = min(max(ix0 + 1, 0), Wd - 1);
          int yc0 = min(max(iy0, 0), Hd - 1), yc1 = min(max(iy0 + 1, 0), Hd - 1);
          v = wi0[k] * rdc(c, yc0 * Wd + xc0) + wi1[k] * rdc(c, yc0 * Wd + xc1)
            + wi2[k] * rdc(c, yc1 * Wd + xc0) + wi3[k] * rdc(c, yc1 * Wd + xc1);
        }
        Ild[idx] = v;
      }
    }
    __syncthreads();                 // srcT reads done; Ild visible
    if (c + 1 < Cd) { if constexpr (SBF) writeB2(); else fillS(c + 1); }

    // ---- outer warp from Ild ----
    float ov[4];
#pragma unroll
    for (int j = 0; j < 4; ++j) {
      float v;
      if (!(fbm & (1 << j))) {
        const float* p = &Ild[lA[j]];
        v = (w00[j] * p[0] + w10[j] * p[1]) + (w01[j] * p[IW] + w11[j] * p[IW + 1]);
      } else {
        uint32_t pk = pxy[j];
        int ix0 = (int)(pk & 0xffffu) - 128;
        int iy0 = (int)(pk >> 16) - 128;
        v = w00[j] * sampleI(c, ix0, iy0)     + w10[j] * sampleI(c, ix0 + 1, iy0)
          + w01[j] * sampleI(c, ix0, iy0 + 1) + w11[j] * sampleI(c, ix0 + 1, iy0 + 1);
      }
      ov[j] = v;
    }
    if (dBF) {
      uint p0 = f2bf_bits(ov[0]) | (f2bf_bits(ov[1]) << 16);
      uint p1 = f2bf_bits(ov[2]) | (f2bf_bits(ov[3]) << 16);
      *reinterpret_cast<uint2*>(dB16 + (long)c * HW + pix) = make_uint2(p0, p1);
    } else {
      *reinterpret_cast<float4*>(dF32 + (long)c * HW + pix)
          = make_float4(ov[0], ov[1], ov[2], ov[3]);
    }
    __syncthreads();                 // Ild reads done; srcT(c+1) landed
  }
}

extern "C" void kernel_launch(void* const* d_in, const int* in_sizes, int n_in,
                              void* d_out, int out_size, void* d_ws, size_t ws_size,
                              hipStream_t stream) {
  const float* feat = (const float*)d_in[0];
  const float* mv   = (const float*)d_in[1];
  float*       out  = (float*)d_out;

  dim3 block(512, 1, 1);
  const long FB = FRAME_BSTRIDE;
  auto mkjob = [](const void* s, long ss, void* d, long ds, const float* fl,
                  int sBF, int dBF) {
    Job j; j.s = s; j.ss = ss; j.d = d; j.ds = ds; j.fl = fl;
    j.sBF = sBF; j.dBF = dBF; return j;
  };
  Job Z = mkjob(nullptr, 0, nullptr, 0, nullptr, 0, 0);
  const float* flj[4] = { mv + 0L * 2 * HW, mv + 1L * 2 * HW,
                          mv + 2L * 2 * HW, mv + 3L * 2 * HW };

  auto launchP = [&](int nj, Job a, Job b, Job c, Job d, Job e) {
    warp_pipe<<<dim3(NWG, nj, 1), block, 0, stream>>>(a, b, c, d, e);
  };

  const size_t need = (size_t)(2 * CHW) * Bd * sizeof(uint16_t);  // ~67 MB

  if (ws_size >= need) {
    uint16_t* W  = (uint16_t*)d_ws;
    const long WB = 2 * CHW;             // ws batch stride (bf16 elems)
    uint16_t* wa = W + 0 * CHW;
    uint16_t* wb = W + 1 * CHW;

    // A1: f1 = warp(feat1,mv0) -> out1 ; wa = warp(feat3,mv2) bf16 ; copy f0.
    launchP(3,
      mkjob(feat + 1 * CHW, FB, out + 1 * CHW, FB, flj[0], 0, 0),
      mkjob(feat + 3 * CHW, FB, wa, WB, flj[2], 0, 1),
      mkjob(feat, FB, out, FB, nullptr, 0, 0), Z, Z);

    // A2: out2 = fused(feat2; inner mv1, outer mv0) ;
    //     wb   = fused(feat4; inner mv3, outer mv2) bf16.
    {
      Job2 a{feat + 2 * CHW, FB, out + 2 * CHW, FB, flj[0], flj[1], 0};
      Job2 d{feat + 4 * CHW, FB, wb, WB, flj[2], flj[3], 1};
      warp_fused2<false><<<dim3(NWG, 2, 1), block, 0, stream>>>(a, d);
    }

    // B: out3 = fused(wa; inner mv1, outer mv0) ;
    //    out4 = fused(wb; inner mv1, outer mv0).
    {
      Job2 a{wa, WB, out + 3 * CHW, FB, flj[0], flj[1], 0};
      Job2 d{wb, WB, out + 4 * CHW, FB, flj[0], flj[1], 0};
      warp_fused2<true><<<dim3(NWG, 2, 1), block, 0, stream>>>(a, d);
    }
  } else {
    // Fallback: all-fp32 via the pipelined kernel, out0 slot as scratch.
    float* S = out;
    auto w1 = [&](const float* s, float* d, int j) {
      launchP(1, mkjob(s, FB, d, FB, flj[j], 0, 0), Z, Z, Z, Z);
    };
    w1(feat + 1 * CHW, out + 1 * CHW, 0);
    w1(feat + 2 * CHW, S, 1);
    w1(S, out + 2 * CHW, 0);
    w1(feat + 3 * CHW, out + 3 * CHW, 2);
    w1(out + 3 * CHW, S, 1);
    w1(S, out + 3 * CHW, 0);
    w1(feat + 4 * CHW, S, 3);
    w1(S, out + 4 * CHW, 2);
    w1(out + 4 * CHW, S, 1);
    w1(S, out + 4 * CHW, 0);
    launchP(1, mkjob(feat, FB, out, FB, nullptr, 0, 0), Z, Z, Z, Z);
  }
}

// Round 14
// 300.030 us; speedup vs baseline: 2.3798x; 2.3798x over previous
//
#include <hip/hip_runtime.h>
#include <stdint.h>

namespace {
constexpr int Wd = 960, Hd = 544, Cd = 16, Id = 5, Bd = 2;
constexpr int HW = Hd * Wd;                       // 522240
constexpr long CHW = (long)Cd * HW;               // 8,355,840
constexpr long FRAME_BSTRIDE = (long)Id * CHW;
constexpr long FLOW_BSTRIDE  = (long)Id * 2 * HW;

constexpr int TSX = 64, TSY = 32;   // output tile, 512 thr x 4 px
constexpr int HALO = 12;            // 3 sigma of 4px flow; tails -> epilogue fixup
constexpr int TWX = TSX + 2 * HALO; // 88
constexpr int TWY = TSY + 2 * HALO; // 56
constexpr int NCHUNK = 20;          // 20 x 256 floats = 5120 >= 88*56 = 4928
constexpr int TILE_F = NCHUNK * 256;  // max read idx 54*88+86+89 = 4927 < 5120
constexpr int GX = Wd / TSX;        // 15
constexpr int GY = Hd / TSY;        // 17
constexpr int NWG = GX * GY * Bd;   // 510
}

struct F2 { float x, y; };
struct Job { const void* s; long ss; void* d; long ds; const float* fl; int sBF, dBF; };

__device__ __forceinline__ uint f2bf_bits(float v) {   // RNE float->bf16
  uint x = __float_as_uint(v);
  return (x + 0x7FFFu + ((x >> 16) & 1u)) >> 16;
}

// ---------- decode helpers ----------
#define DECODE_TILE()                                                        \
  const int orig = blockIdx.x;                                               \
  const int xcd  = orig & 7;                                                 \
  constexpr int q = NWG / 8, r = NWG % 8;                                    \
  const int wgid = (xcd < r ? xcd * (q + 1) : r * (q + 1) + (xcd - r) * q)   \
                 + (orig >> 3);                                              \
  const int b   = wgid / (GX * GY);                                          \
  const int rem = wgid - b * (GX * GY);                                      \
  const int tyb = rem / GX;                                                  \
  const int txb = rem - tyb * GX;                                            \
  const int X0 = txb * TSX;                                                  \
  const int Y0 = tyb * TSY;                                                  \
  const int t   = threadIdx.x;                                               \
  const int x   = X0 + ((t & 15) << 2);                                      \
  const int y   = Y0 + (t >> 4);                                             \
  const int pix = y * Wd + x;

#define PRECOMPUTE_WEIGHTS()                                                 \
  float4 fxv = *reinterpret_cast<const float4*>(fl + pix);                   \
  float4 fyv = *reinterpret_cast<const float4*>(fl + HW + pix);              \
  float w00[4], w10[4], w01[4], w11[4];                                      \
  int lA[4]; uint32_t pxy[4]; int fbm = 0;                                   \
  _Pragma("unroll")                                                          \
  for (int j = 0; j < 4; ++j) {                                              \
    float fx = (j==0)?fxv.x:(j==1)?fxv.y:(j==2)?fxv.z:fxv.w;                 \
    float fy = (j==0)?fyv.x:(j==1)?fyv.y:(j==2)?fyv.z:fyv.w;                 \
    float gx = (float)(x + j) + fx;                                          \
    float gy = (float)y + fy;                                                \
    float x0f = floorf(gx), y0f = floorf(gy);                                \
    float wx = gx - x0f, wy = gy - y0f;                                      \
    bool vx0 = (x0f >= 0.f) && (x0f <= (float)(Wd - 1));                     \
    bool vx1 = (x0f + 1.f >= 0.f) && (x0f + 1.f <= (float)(Wd - 1));         \
    bool vy0 = (y0f >= 0.f) && (y0f <= (float)(Hd - 1));                     \
    bool vy1 = (y0f + 1.f >= 0.f) && (y0f + 1.f <= (float)(Hd - 1));         \
    w00[j] = (1.f-wx)*(1.f-wy) * ((vx0 && vy0) ? 1.f : 0.f);                 \
    w10[j] = wx*(1.f-wy)       * ((vx1 && vy0) ? 1.f : 0.f);                 \
    w01[j] = (1.f-wx)*wy       * ((vx0 && vy1) ? 1.f : 0.f);                 \
    w11[j] = wx*wy             * ((vx1 && vy1) ? 1.f : 0.f);                 \
    int ix0 = (int)x0f;                                                      \
    int iy0 = (int)y0f;                                                      \
    int lx = ix0 - (X0 - HALO);                                              \
    int ly = iy0 - (Y0 - HALO);                                              \
    bool ft = (lx >= 0) & (lx <= TWX - 2) & (ly >= 0) & (ly <= TWY - 2);     \
    if (!ft) fbm |= (1 << j);                                                \
    int lxc = min(max(lx, 0), TWX - 2), lyc = min(max(ly, 0), TWY - 2);      \
    lA[j] = (lyc * TWX + lxc) * 4;                                           \
    uint32_t px_ = (uint32_t)min(max(ix0 + 128, 0), 65535);                  \
    uint32_t py_ = (uint32_t)min(max(iy0 + 128, 0), 65535);                  \
    pxy[j] = px_ | (py_ << 16);                                              \
  }

#define PRECOMPUTE_GOFF()                                                    \
  const int lane = t & 63;                                                   \
  const int wv   = t >> 6;                                                   \
  const int nck  = (wv < 4) ? 3 : 2;                                         \
  int goff[3];                                                               \
  _Pragma("unroll")                                                          \
  for (int k = 0; k < 3; ++k) {                                              \
    int ck = wv + 8 * k;                                                     \
    if (ck < NCHUNK) {                                                       \
      int foff = ck * 256 + lane * 4;                                        \
      int ly = foff / TWX;                                                   \
      int lx = foff - ly * TWX;                                              \
      int gxc = min(max(X0 - HALO + lx, 0), Wd - 4);                         \
      int gyc = min(max(Y0 - HALO + ly, 0), Hd - 1);                         \
      goff[k] = gyc * Wd + gxc;                                              \
    }                                                                        \
  }

#define WAITV(n3, n2)                                                        \
  if (wv < 4) { asm volatile("s_waitcnt vmcnt(" #n3 ")" ::: "memory"); }     \
  else        { asm volatile("s_waitcnt vmcnt(" #n2 ")" ::: "memory"); }

// =============== pipelined fp32-source kernel (stage A + fallback) =========
#define PHASE(c, n3, n2)                                                     \
  WAITV(n3, n2);                                                             \
  __builtin_amdgcn_s_barrier();                                              \
  __builtin_amdgcn_sched_barrier(0);                                         \
  if ((c) + 3 < Cd) fillq(((c) + 3) & 3, (c) + 3);                           \
  comp(c);

__global__ __launch_bounds__(512, 4) void warp_pipe(
    Job j0, Job j1, Job j2, Job j3, Job j4)
{
  __shared__ float tile[4 * TILE_F];   // 80 KB -> 2 blocks/CU

  const int jb = blockIdx.y;
  Job J = j0;
  if      (jb == 1) J = j1;
  else if (jb == 2) J = j2;
  else if (jb == 3) J = j3;
  else if (jb == 4) J = j4;

  DECODE_TILE();

  const float* sF32 = (const float*)J.s + (long)b * J.ss;
  float*       dF32 = (float*)J.d + (long)b * J.ds;
  uint16_t*    dB16 = (uint16_t*)J.d + (long)b * J.ds;
  const bool dBF = J.dBF != 0;

  if (J.fl == nullptr) {   // plain fp32 copy job (frame 0); no barriers
#pragma unroll
    for (int c = 0; c < Cd; ++c)
      *reinterpret_cast<float4*>(dF32 + (long)c * HW + pix)
          = *reinterpret_cast<const float4*>(sF32 + (long)c * HW + pix);
    return;
  }

  const float* fl = J.fl + (long)b * FLOW_BSTRIDE;
  PRECOMPUTE_WEIGHTS();
  PRECOMPUTE_GOFF();

  auto fillq = [&](int buf, int c) {
    const float* sC = sF32 + (long)c * HW;
    float* base = &tile[buf * TILE_F];
#pragma unroll
    for (int k = 0; k < 3; ++k) {
      if (k < nck) {
        __builtin_amdgcn_global_load_lds(
            (__attribute__((address_space(1))) void*)(void*)(sC + goff[k]),
            (__attribute__((address_space(3))) void*)&base[(wv + 8 * k) * 256],
            16, 0, 0);
      }
    }
  };

  auto comp = [&](int c) {
    const float* tb = &tile[(c & 3) * TILE_F];
    float ov[4];
#pragma unroll
    for (int j = 0; j < 4; ++j) {
      F2 r0 = *(const F2*)((const char*)tb + lA[j]);
      F2 r1 = *(const F2*)((const char*)tb + lA[j] + TWX * 4);
      ov[j] = (w00[j] * r0.x + w10[j] * r0.y) + (w01[j] * r1.x + w11[j] * r1.y);
    }
    if (dBF) {
      uint p0 = f2bf_bits(ov[0]) | (f2bf_bits(ov[1]) << 16);
      uint p1 = f2bf_bits(ov[2]) | (f2bf_bits(ov[3]) << 16);
      *reinterpret_cast<uint2*>(dB16 + (long)c * HW + pix) = make_uint2(p0, p1);
    } else {
      *reinterpret_cast<float4*>(dF32 + (long)c * HW + pix)
          = make_float4(ov[0], ov[1], ov[2], ov[3]);
    }
  };

  fillq(0, 0); fillq(1, 1); fillq(2, 2);

  PHASE(0, 6, 4)  PHASE(1, 7, 5)  PHASE(2, 8, 6)
  PHASE(3, 9, 7)  PHASE(4, 9, 7)  PHASE(5, 9, 7)
  PHASE(6, 9, 7)  PHASE(7, 9, 7)  PHASE(8, 9, 7)
  PHASE(9, 9, 7)  PHASE(10, 9, 7) PHASE(11, 9, 7)
  PHASE(12, 9, 7) PHASE(13, 9, 7)
  PHASE(14, 6, 5) PHASE(15, 3, 3)

  if (fbm) {
    asm volatile("s_waitcnt vmcnt(0)" ::: "memory");
    for (int c = 0; c < Cd; ++c) {
      const float* sC = sF32 + (long)c * HW;
#pragma unroll
      for (int j = 0; j < 4; ++j) {
        if (fbm & (1 << j)) {
          uint32_t p = pxy[j];
          int ix0 = (int)(p & 0xffffu) - 128;
          int iy0 = (int)(p >> 16) - 128;
          int xc0 = min(max(ix0, 0), Wd - 1), xc1 = min(max(ix0 + 1, 0), Wd - 1);
          int yc0 = min(max(iy0, 0), Hd - 1), yc1 = min(max(iy0 + 1, 0), Hd - 1);
          float v = w00[j] * sC[yc0 * Wd + xc0] + w10[j] * sC[yc0 * Wd + xc1]
                  + w01[j] * sC[yc1 * Wd + xc0] + w11[j] * sC[yc1 * Wd + xc1];
          if (dBF) dB16[(long)c * HW + pix + j] = (uint16_t)f2bf_bits(v);
          else     dF32[(long)c * HW + pix + j] = v;
        }
      }
    }
  }
}

// =============== bf16-source kernel (stages B/C/D) — round-8 proven ========
__global__ __launch_bounds__(512) void warp_bf16(
    Job j0, Job j1, Job j2, Job j3, Job j4)
{
  __shared__ float tile[2][TILE_F];   // 40 KB

  const int jb = blockIdx.y;
  Job J = j0;
  if      (jb == 1) J = j1;
  else if (jb == 2) J = j2;

  DECODE_TILE();

  const uint16_t* sB16 = (const uint16_t*)J.s + (long)b * J.ss;
  float*          dF32 = (float*)J.d + (long)b * J.ds;
  uint16_t*       dB16 = (uint16_t*)J.d + (long)b * J.ds;
  const bool dBF = J.dBF != 0;

  const float* fl = J.fl + (long)b * FLOW_BSTRIDE;
  PRECOMPUTE_WEIGHTS();
  PRECOMPUTE_GOFF();

  // bf16 fill: reg-staged (load early / cvt+ds_write late).
  uint2 ld[3];
  auto loadB = [&](int c) {
    const uint* gp = (const uint*)(sB16 + (long)c * HW);
#pragma unroll
    for (int k = 0; k < 3; ++k)
      if (k < nck) ld[k] = *(const uint2*)(gp + (goff[k] >> 1));
  };
  auto writeB = [&](int nb) {
#pragma unroll
    for (int k = 0; k < 3; ++k) {
      if (k < nck) {
        float4 f;
        f.x = __uint_as_float(ld[k].x << 16);
        f.y = __uint_as_float(ld[k].x & 0xFFFF0000u);
        f.z = __uint_as_float(ld[k].y << 16);
        f.w = __uint_as_float(ld[k].y & 0xFFFF0000u);
        *reinterpret_cast<float4*>(&tile[nb][(wv + 8 * k) * 256 + lane * 4]) = f;
      }
    }
  };

  loadB(0); writeB(0);

#pragma unroll
  for (int c = 0; c < Cd; ++c) {
    __syncthreads();
    const bool pre = (c + 1 < Cd);
    if (pre) loadB(c + 1);

    const float* tb = tile[c & 1];
    float ov[4];
#pragma unroll
    for (int j = 0; j < 4; ++j) {
      float v;
      if (!(fbm & (1 << j))) {
        F2 r0 = *(const F2*)((const char*)tb + lA[j]);
        F2 r1 = *(const F2*)((const char*)tb + lA[j] + TWX * 4);
        v = (w00[j] * r0.x + w10[j] * r0.y) + (w01[j] * r1.x + w11[j] * r1.y);
      } else {
        uint32_t p = pxy[j];
        int ix0 = (int)(p & 0xffffu) - 128;
        int iy0 = (int)(p >> 16) - 128;
        int xc0 = min(max(ix0, 0), Wd - 1), xc1 = min(max(ix0 + 1, 0), Wd - 1);
        int yc0 = min(max(iy0, 0), Hd - 1), yc1 = min(max(iy0 + 1, 0), Hd - 1);
        const uint16_t* su = sB16 + (long)c * HW;
        float v00 = __uint_as_float((uint)su[yc0 * Wd + xc0] << 16);
        float v10 = __uint_as_float((uint)su[yc0 * Wd + xc1] << 16);
        float v01 = __uint_as_float((uint)su[yc1 * Wd + xc0] << 16);
        float v11 = __uint_as_float((uint)su[yc1 * Wd + xc1] << 16);
        v = w00[j] * v00 + w10[j] * v10 + w01[j] * v01 + w11[j] * v11;
      }
      ov[j] = v;
    }
    if (dBF) {
      uint p0 = f2bf_bits(ov[0]) | (f2bf_bits(ov[1]) << 16);
      uint p1 = f2bf_bits(ov[2]) | (f2bf_bits(ov[3]) << 16);
      *reinterpret_cast<uint2*>(dB16 + (long)c * HW + pix) = make_uint2(p0, p1);
    } else {
      *reinterpret_cast<float4*>(dF32 + (long)c * HW + pix)
          = make_float4(ov[0], ov[1], ov[2], ov[3]);
    }
    if (pre) writeB((c + 1) & 1);
  }
}

extern "C" void kernel_launch(void* const* d_in, const int* in_sizes, int n_in,
                              void* d_out, int out_size, void* d_ws, size_t ws_size,
                              hipStream_t stream) {
  const float* feat = (const float*)d_in[0];
  const float* mv   = (const float*)d_in[1];
  float*       out  = (float*)d_out;

  dim3 block(512, 1, 1);
  const long FB = FRAME_BSTRIDE;
  auto mkjob = [](const void* s, long ss, void* d, long ds, const float* fl,
                  int sBF, int dBF) {
    Job j; j.s = s; j.ss = ss; j.d = d; j.ds = ds; j.fl = fl;
    j.sBF = sBF; j.dBF = dBF; return j;
  };
  Job Z = mkjob(nullptr, 0, nullptr, 0, nullptr, 0, 0);
  const float* flj[4] = { mv + 0L * 2 * HW, mv + 1L * 2 * HW,
                          mv + 2L * 2 * HW, mv + 3L * 2 * HW };

  auto launchP = [&](int nj, Job a, Job b, Job c, Job d, Job e) {
    warp_pipe<<<dim3(NWG, nj, 1), block, 0, stream>>>(a, b, c, d, e);
  };
  auto launchB = [&](int nj, Job a, Job b, Job c) {
    warp_bf16<<<dim3(NWG, nj, 1), block, 0, stream>>>(a, b, c, Z, Z);
  };

  const size_t need = (size_t)(4 * CHW) * Bd * sizeof(uint16_t);  // 134 MB

  if (ws_size >= need) {
    uint16_t* W  = (uint16_t*)d_ws;
    const long WB = 4 * CHW;               // ws batch stride (bf16 elems)
    uint16_t* wa = W + 0 * CHW;
    uint16_t* wb = W + 1 * CHW;
    uint16_t* wd = W + 2 * CHW;
    uint16_t* wc = W + 3 * CHW;
    uint16_t* we = (uint16_t*)(out + 4 * CHW);   // out4 slot as bf16 scratch
    const long EB = 2 * FB;                // out batch stride in bf16 elems

    // A (pipelined fp32): f1 final; f2->a, f3->b, f4->d (bf16); frame-0 copy.
    launchP(5,
      mkjob(feat + 1 * CHW, FB, out + 1 * CHW, FB, flj[0], 0, 0),
      mkjob(feat + 2 * CHW, FB, wa, WB, flj[1], 0, 1),
      mkjob(feat + 3 * CHW, FB, wb, WB, flj[2], 0, 1),
      mkjob(feat + 4 * CHW, FB, wd, WB, flj[3], 0, 1),
      mkjob(feat, FB, out, FB, nullptr, 0, 0));
    // B: a->out2 final; b->c (bf16); d->e (bf16, in out4 slot).
    launchB(3,
      mkjob(wa, WB, out + 2 * CHW, FB, flj[0], 1, 0),
      mkjob(wb, WB, wc, WB, flj[1], 1, 1),
      mkjob(wd, WB, we, EB, flj[2], 1, 1));
    // C: c->out3 final; e->f (bf16, reuse slot a).
    launchB(2,
      mkjob(wc, WB, out + 3 * CHW, FB, flj[0], 1, 0),
      mkjob(we, EB, wa, WB, flj[1], 1, 1), Z);
    // D: f->out4 final (overwrites e, dead).
    launchB(1, mkjob(wa, WB, out + 4 * CHW, FB, flj[0], 1, 0), Z, Z);
  } else {
    // Fallback: all-fp32 via the pipelined kernel, out0 slot as scratch.
    float* S = out;
    auto w1 = [&](const float* s, float* d, int j) {
      launchP(1, mkjob(s, FB, d, FB, flj[j], 0, 0), Z, Z, Z, Z);
    };
    w1(feat + 1 * CHW, out + 1 * CHW, 0);
    w1(feat + 2 * CHW, S, 1);
    w1(S, out + 2 * CHW, 0);
    w1(feat + 3 * CHW, out + 3 * CHW, 2);
    w1(out + 3 * CHW, S, 1);
    w1(S, out + 3 * CHW, 0);
    w1(feat + 4 * CHW, S, 3);
    w1(S, out + 4 * CHW, 2);
    w1(out + 4 * CHW, S, 1);
    w1(S, out + 4 * CHW, 0);
    launchP(1, mkjob(feat, FB, out, FB, nullptr, 0, 0), Z, Z, Z, Z);
  }
}